// Round 1
// baseline (695.824 us; speedup 1.0000x reference)
//
#include <hip/hip_runtime.h>

using f16 = _Float16;
typedef _Float16 h8 __attribute__((ext_vector_type(8)));
typedef _Float16 h4 __attribute__((ext_vector_type(4)));
typedef float f4 __attribute__((ext_vector_type(4)));
typedef unsigned int u32;
typedef unsigned long long u64;

#define DEVI static __device__ __forceinline__

DEVI f4 mfma16(h8 a, h8 b, f4 c) {
  return __builtin_amdgcn_mfma_f32_16x16x32_f16(a, b, c, 0, 0, 0);
}

// async global->LDS, 16B per lane. lds base must be wave-uniform; HW scatters lane i at base + i*16.
DEVI void gl_lds16(const f16* g, f16* l) {
  __builtin_amdgcn_global_load_lds(
      (const __attribute__((address_space(1))) u32*)g,
      (__attribute__((address_space(3))) u32*)l, 16, 0, 0);
}

DEVI u32 pkh2(float a, float b) {
  union { f16 h[2]; u32 u; } x;
  x.h[0] = (f16)a; x.h[1] = (f16)b;
  return x.u;
}

// ---------------- fp32 -> fp16 convert ----------------
typedef float fv4 __attribute__((ext_vector_type(4)));

__global__ __launch_bounds__(256) void k_cvt(const float* __restrict__ in,
                                             f16* __restrict__ out, int n4) {
  int i = blockIdx.x * 256 + threadIdx.x;
  if (i >= n4) return;
  fv4 v = ((const fv4*)in)[i];
  h4 o;
  o[0] = (f16)v[0]; o[1] = (f16)v[1]; o[2] = (f16)v[2]; o[3] = (f16)v[3];
  ((h4*)out)[i] = o;
}

// ---------------- RoPE cos/sin table: tbl[t][i] = {cos,sin}(t * 10000^(-i/64)) ----------------
__global__ __launch_bounds__(256) void k_rope_tbl(float* __restrict__ tbl) {
  int i = blockIdx.x * 256 + threadIdx.x;  // 2048*64
  int t = i >> 6, d = i & 63;
  float invf = exp2f(-(float)d * (13.287712379549449f / 64.f));
  float a = (float)t * invf;
  tbl[2 * i]     = cosf(a);
  tbl[2 * i + 1] = sinf(a);
}

// ---------------- GEMM: C[M][N] = A[M][K] * Bt[N][K]^T + bias, m97 structure ----------------
// 128x128 tile, BK=64, 4 waves (2x2 of 64x64), 16x16x32 f16 MFMA, global_load_lds staging.
template <int F32OUT>
__global__ __launch_bounds__(256) void k_gemm_bt(const f16* __restrict__ A,
                                                 const f16* __restrict__ Bt,
                                                 const float* __restrict__ bias,
                                                 void* __restrict__ Cp,
                                                 int M, int N, int K) {
  __shared__ f16 lds[2 * 128 * 64];
  f16* sA = lds;
  f16* sB = lds + 128 * 64;
  const int tid = threadIdx.x;
  const int w = tid >> 6, lane = tid & 63;
  const int g = lane >> 4, colq = lane & 15;
  const int wr = w >> 1, wc = w & 1;
  const int bm = blockIdx.y, bn = blockIdx.x;

  f4 acc[4][4] = {};
  const int nk = K >> 6;
  const int lrow = lane >> 3;   // 0..7 within seg
  const int lch = lane & 7;     // 16B chunk within row

  for (int k0i = 0; k0i < nk; ++k0i) {
    const int k0 = k0i << 6;
#pragma unroll
    for (int c = 0; c < 4; ++c) {
      const int seg = c * 4 + w;            // wave-uniform
      const int row = seg * 8 + lrow;       // 0..127
      const f16* ga = A + (size_t)(bm * 128 + row) * K + k0 + lch * 8;
      const f16* gb = Bt + (size_t)(bn * 128 + row) * K + k0 + lch * 8;
      gl_lds16(ga, sA + seg * 512);
      gl_lds16(gb, sB + seg * 512);
    }
    __syncthreads();
#pragma unroll
    for (int kk = 0; kk < 64; kk += 32) {
      h8 af[4], bf[4];
#pragma unroll
      for (int m = 0; m < 4; ++m)
        af[m] = *(const h8*)(sA + (wr * 64 + m * 16 + colq) * 64 + kk + g * 8);
#pragma unroll
      for (int n = 0; n < 4; ++n)
        bf[n] = *(const h8*)(sB + (wc * 64 + n * 16 + colq) * 64 + kk + g * 8);
#pragma unroll
      for (int m = 0; m < 4; ++m)
#pragma unroll
        for (int n = 0; n < 4; ++n) acc[m][n] = mfma16(af[m], bf[n], acc[m][n]);
    }
    __syncthreads();
  }

#pragma unroll
  for (int n = 0; n < 4; ++n) {
    const int col = bn * 128 + wc * 64 + n * 16 + colq;
    const float bv = bias[col];
#pragma unroll
    for (int m = 0; m < 4; ++m) {
      const int row0 = bm * 128 + wr * 64 + m * 16 + 4 * g;
#pragma unroll
      for (int r = 0; r < 4; ++r) {
        float v = acc[m][n][r] + bv;
        if constexpr (F32OUT) {
          ((float*)Cp)[(size_t)(row0 + r) * N + col] = v;
        } else {
          ((f16*)Cp)[(size_t)(row0 + r) * N + col] = (f16)v;
        }
      }
    }
  }
}

// ---------------- RoPE apply: qkv[bt][f] -> Q[bh][t][d], K[bh][t][d] ----------------
// Q gets * (1/sqrt(128)) * log2(e) folded in (attention then uses exp2 with no extra scale).
__global__ __launch_bounds__(256) void k_rope(const f16* __restrict__ qkv,
                                              const float* __restrict__ tbl,
                                              f16* __restrict__ Q, f16* __restrict__ K) {
  int i = blockIdx.x * 256 + threadIdx.x;  // < 4096*16*64
  int d = i & 63;
  int h = (i >> 6) & 15;
  int bt = i >> 10;
  int t = bt & 2047;
  int bh = ((bt >> 11) << 4) | h;
  union { u32 u; f16 h2[2]; } qa, ka, qo, ko;
  qa.u = *(const u32*)(qkv + (size_t)bt * 6144 + h * 128 + 2 * d);
  ka.u = *(const u32*)(qkv + (size_t)bt * 6144 + 2048 + h * 128 + 2 * d);
  float c = tbl[2 * (t * 64 + d)];
  float s = tbl[2 * (t * 64 + d) + 1];
  float q0f = (float)qa.h2[0], q1f = (float)qa.h2[1];
  float k0f = (float)ka.h2[0], k1f = (float)ka.h2[1];
  const float SQ = 0.088388347648318447f * 1.4426950408889634f;
  qo.h2[0] = (f16)((q0f * c - q1f * s) * SQ);
  qo.h2[1] = (f16)((q1f * c + q0f * s) * SQ);
  ko.h2[0] = (f16)(k0f * c - k1f * s);
  ko.h2[1] = (f16)(k1f * c + k0f * s);
  *(u32*)(Q + ((size_t)bh * 2048 + t) * 128 + 2 * d) = qo.u;
  *(u32*)(K + ((size_t)bh * 2048 + t) * 128 + 2 * d) = ko.u;
}

// ---------------- V transpose: qkv[bt][4096 + h*128 + d] -> Vt[bh][d][t] ----------------
__global__ __launch_bounds__(256) void k_vtrans(const f16* __restrict__ qkv,
                                                f16* __restrict__ Vt) {
  __shared__ f16 ldsT[128 * 40];
  const int bh = blockIdx.y, t0 = blockIdx.x * 32;
  const int b = bh >> 4, h = bh & 15;
  const int tid = threadIdx.x;
#pragma unroll
  for (int cc = 0; cc < 2; ++cc) {
    int task = tid + cc * 256;  // 0..511
    int row = task >> 4;        // t-local 0..31
    int ch = task & 15;         // d chunk of 8
    h8 v = *(const h8*)(qkv + (size_t)(b * 2048 + t0 + row) * 6144 + 4096 + h * 128 + ch * 8);
#pragma unroll
    for (int j = 0; j < 8; ++j) ldsT[(ch * 8 + j) * 40 + row] = v[j];
  }
  __syncthreads();
  int d = tid >> 1, seg = tid & 1;
  h8 v0 = *(const h8*)(ldsT + d * 40 + seg * 16);
  h8 v1 = *(const h8*)(ldsT + d * 40 + seg * 16 + 8);
  f16* dst = Vt + ((size_t)bh * 128 + d) * 2048 + t0 + seg * 16;
  *(h8*)dst = v0;
  *(h8*)(dst + 8) = v1;
}

// ---------------- causal flash attention ----------------
// grid (T/64, B*H), 4 waves/block, each wave owns 16 q-rows. KVBLK=32.
// Swapped QK^T: St[p][q] = sum_d K[p][d] Q[q][d] -> C-frag col = q (lane&15), row = p.
// PV as O^T[d][q] = sum_p V^T[d][p] P^T[p][q].
__global__ __launch_bounds__(256) void k_attn(const f16* __restrict__ Q,
                                              const f16* __restrict__ K,
                                              const f16* __restrict__ Vt,
                                              f16* __restrict__ O) {
  const int tid = threadIdx.x;
  const int w = tid >> 6, lane = tid & 63;
  const int g = lane >> 4, q = lane & 15;
  const int bh = blockIdx.y;
  const int q0 = (blockIdx.x * 4 + w) * 16;

  const f16* Qb = Q + ((size_t)bh * 2048 + q0 + q) * 128;
  const f16* Kb = K + (size_t)bh * 2048 * 128 + (size_t)q * 128 + g * 8;
  const f16* Vb = Vt + ((size_t)bh * 128 + q) * 2048 + g * 8;

  h8 qf[4];
#pragma unroll
  for (int d4 = 0; d4 < 4; ++d4) qf[d4] = *(const h8*)(Qb + d4 * 32 + g * 8);

  f4 ot[8] = {};
  float mrun = -3.0e38f, lrun = 0.f;

  for (int kv0 = 0; kv0 < q0 + 16; kv0 += 32) {
    f4 st0 = {0.f, 0.f, 0.f, 0.f}, st1 = {0.f, 0.f, 0.f, 0.f};
    const f16* Kr = Kb + (size_t)kv0 * 128;
#pragma unroll
    for (int d4 = 0; d4 < 4; ++d4) {
      h8 kf0 = *(const h8*)(Kr + d4 * 32);
      h8 kf1 = *(const h8*)(Kr + 2048 + d4 * 32);  // +16 rows
      st0 = mfma16(kf0, qf[d4], st0);
      st1 = mfma16(kf1, qf[d4], st1);
    }
    if (kv0 + 31 > q0) {  // causal mask (only near diagonal)
#pragma unroll
      for (int r = 0; r < 4; ++r) {
        if (kv0 + 4 * g + r > q0 + q) st0[r] = -3.0e38f;
        if (kv0 + 16 + 4 * g + r > q0 + q) st1[r] = -3.0e38f;
      }
    }
    // online softmax over column q (lanes {q, q+16, q+32, q+48})
    float pm = fmaxf(fmaxf(fmaxf(st0[0], st0[1]), fmaxf(st0[2], st0[3])),
                     fmaxf(fmaxf(st1[0], st1[1]), fmaxf(st1[2], st1[3])));
    pm = fmaxf(pm, __shfl_xor(pm, 16));
    pm = fmaxf(pm, __shfl_xor(pm, 32));
    float mnew = fmaxf(mrun, pm);
    float corr = exp2f(mrun - mnew);
    float ps = 0.f;
#pragma unroll
    for (int r = 0; r < 4; ++r) {
      st0[r] = exp2f(st0[r] - mnew);
      st1[r] = exp2f(st1[r] - mnew);
      ps += st0[r] + st1[r];
    }
    ps += __shfl_xor(ps, 16);
    ps += __shfl_xor(ps, 32);
    lrun = lrun * corr + ps;
    mrun = mnew;
#pragma unroll
    for (int dt = 0; dt < 8; ++dt) ot[dt] *= corr;

    // P (C-frag layout) -> PV B-frag: b[jj] = P^T[g*8+jj][q]
    u32 wA0 = pkh2(st0[0], st0[1]), wB0 = pkh2(st0[2], st0[3]);
    u32 wA1 = pkh2(st1[0], st1[1]), wB1 = pkh2(st1[2], st1[3]);
    int s0 = ((g & 1) << 5) | q;
    u32 a0 = (u32)__shfl((int)wA0, s0),      a1 = (u32)__shfl((int)wA1, s0);
    u32 b0 = (u32)__shfl((int)wB0, s0),      b1 = (u32)__shfl((int)wB1, s0);
    u32 c0 = (u32)__shfl((int)wA0, s0 + 16), c1 = (u32)__shfl((int)wA1, s0 + 16);
    u32 d0 = (u32)__shfl((int)wB0, s0 + 16), d1 = (u32)__shfl((int)wB1, s0 + 16);
    union { u32 u[4]; h8 h; } pb;
    const bool hi = g >= 2;  // tile = g>>1
    pb.u[0] = hi ? a1 : a0;
    pb.u[1] = hi ? b1 : b0;
    pb.u[2] = hi ? c1 : c0;
    pb.u[3] = hi ? d1 : d0;

    const f16* Vr = Vb + kv0;
#pragma unroll
    for (int dt = 0; dt < 8; ++dt) {
      h8 vf = *(const h8*)(Vr + (size_t)dt * 16 * 2048);
      ot[dt] = mfma16(vf, pb.h, ot[dt]);
    }
  }

  float linv = 1.0f / lrun;
  f16* Ob = O + ((size_t)(bh >> 4) * 2048 + q0 + q) * 2048 + (bh & 15) * 128 + 4 * g;
#pragma unroll
  for (int dt = 0; dt < 8; ++dt) {
    union { f16 hh[4]; u64 u; } o;
#pragma unroll
    for (int r = 0; r < 4; ++r) o.hh[r] = (f16)(ot[dt][r] * linv);
    *(u64*)(Ob + dt * 16) = o.u;
  }
}

// ---------------- launch ----------------
extern "C" void kernel_launch(void* const* d_in, const int* in_sizes, int n_in,
                              void* d_out, int out_size, void* d_ws, size_t ws_size,
                              hipStream_t stream) {
  (void)in_sizes; (void)n_in; (void)out_size; (void)ws_size;
  const float* x    = (const float*)d_in[0];
  const float* Wqkv = (const float*)d_in[1];
  const float* bqkv = (const float*)d_in[2];
  const float* Wo   = (const float*)d_in[3];
  const float* bo   = (const float*)d_in[4];

  char* ws = (char*)d_ws;
  f16* xb    = (f16*)ws; ws += (size_t)4096 * 2048 * 2;
  f16* wqkvb = (f16*)ws; ws += (size_t)6144 * 2048 * 2;
  f16* wob   = (f16*)ws; ws += (size_t)2048 * 2048 * 2;
  f16* qkvb  = (f16*)ws; ws += (size_t)4096 * 6144 * 2;
  f16* Qb    = (f16*)ws; ws += (size_t)32 * 2048 * 128 * 2;
  f16* Kb    = (f16*)ws; ws += (size_t)32 * 2048 * 128 * 2;
  f16* Vtb   = (f16*)ws; ws += (size_t)32 * 128 * 2048 * 2;
  f16* attb  = (f16*)ws; ws += (size_t)4096 * 2048 * 2;
  float* tbl = (float*)ws; ws += (size_t)2048 * 64 * 2 * 4;

  k_cvt<<<8192, 256, 0, stream>>>(x, xb, 2097152);
  k_cvt<<<12288, 256, 0, stream>>>(Wqkv, wqkvb, 3145728);
  k_cvt<<<4096, 256, 0, stream>>>(Wo, wob, 1048576);
  k_rope_tbl<<<512, 256, 0, stream>>>(tbl);

  k_gemm_bt<0><<<dim3(48, 32), 256, 0, stream>>>(xb, wqkvb, bqkv, qkvb, 4096, 6144, 2048);

  k_rope<<<16384, 256, 0, stream>>>(qkvb, tbl, Qb, Kb);
  k_vtrans<<<dim3(64, 32), 256, 0, stream>>>(qkvb, Vtb);

  k_attn<<<dim3(32, 32), 256, 0, stream>>>(Qb, Kb, Vtb, attb);

  k_gemm_bt<1><<<dim3(16, 32), 256, 0, stream>>>(attb, wob, bo, d_out, 4096, 2048, 2048);
}

// Round 2
// 536.627 us; speedup vs baseline: 1.2967x; 1.2967x over previous
//
#include <hip/hip_runtime.h>

using f16 = _Float16;
typedef _Float16 h8 __attribute__((ext_vector_type(8)));
typedef _Float16 h4 __attribute__((ext_vector_type(4)));
typedef float f4 __attribute__((ext_vector_type(4)));
typedef unsigned int u32;
typedef unsigned long long u64;

#define DEVI static __device__ __forceinline__

DEVI f4 mfma16(h8 a, h8 b, f4 c) {
  return __builtin_amdgcn_mfma_f32_16x16x32_f16(a, b, c, 0, 0, 0);
}

// async global->LDS, 16B per lane. lds base must be wave-uniform; HW scatters lane i at base + i*16.
DEVI void gl_lds16(const f16* g, f16* l) {
  __builtin_amdgcn_global_load_lds(
      (const __attribute__((address_space(1))) u32*)g,
      (__attribute__((address_space(3))) u32*)l, 16, 0, 0);
}

DEVI u32 pkh2(float a, float b) {
  union { f16 h[2]; u32 u; } x;
  x.h[0] = (f16)a; x.h[1] = (f16)b;
  return x.u;
}

// ---------------- fp32 -> fp16 convert ----------------
typedef float fv4 __attribute__((ext_vector_type(4)));

__global__ __launch_bounds__(256) void k_cvt(const float* __restrict__ in,
                                             f16* __restrict__ out, int n4) {
  int i = blockIdx.x * 256 + threadIdx.x;
  if (i >= n4) return;
  fv4 v = ((const fv4*)in)[i];
  h4 o;
  o[0] = (f16)v[0]; o[1] = (f16)v[1]; o[2] = (f16)v[2]; o[3] = (f16)v[3];
  ((h4*)out)[i] = o;
}

// ---------------- RoPE cos/sin table: tbl[t][i] = {cos,sin}(t * 10000^(-i/64)) ----------------
__global__ __launch_bounds__(256) void k_rope_tbl(float* __restrict__ tbl) {
  int i = blockIdx.x * 256 + threadIdx.x;  // 2048*64
  int t = i >> 6, d = i & 63;
  float invf = exp2f(-(float)d * (13.287712379549449f / 64.f));
  float a = (float)t * invf;
  tbl[2 * i]     = cosf(a);
  tbl[2 * i + 1] = sinf(a);
}

// ---------------- GEMM: C[M][N] = A[M][K] * Bt[N][K]^T + bias, m97 structure ----------------
// 128x128 tile, BK=64, 4 waves (2x2 of 64x64), 16x16x32 f16 MFMA, global_load_lds staging.
template <int F32OUT>
__global__ __launch_bounds__(256) void k_gemm_bt(const f16* __restrict__ A,
                                                 const f16* __restrict__ Bt,
                                                 const float* __restrict__ bias,
                                                 void* __restrict__ Cp,
                                                 int M, int N, int K) {
  __shared__ f16 lds[2 * 128 * 64];
  f16* sA = lds;
  f16* sB = lds + 128 * 64;
  const int tid = threadIdx.x;
  const int w = tid >> 6, lane = tid & 63;
  const int g = lane >> 4, colq = lane & 15;
  const int wr = w >> 1, wc = w & 1;
  const int bm = blockIdx.y, bn = blockIdx.x;

  f4 acc[4][4] = {};
  const int nk = K >> 6;
  const int lrow = lane >> 3;   // 0..7 within seg
  const int lch = lane & 7;     // 16B chunk within row

  for (int k0i = 0; k0i < nk; ++k0i) {
    const int k0 = k0i << 6;
#pragma unroll
    for (int c = 0; c < 4; ++c) {
      const int seg = c * 4 + w;            // wave-uniform
      const int row = seg * 8 + lrow;       // 0..127
      const f16* ga = A + (size_t)(bm * 128 + row) * K + k0 + lch * 8;
      const f16* gb = Bt + (size_t)(bn * 128 + row) * K + k0 + lch * 8;
      gl_lds16(ga, sA + seg * 512);
      gl_lds16(gb, sB + seg * 512);
    }
    __syncthreads();
#pragma unroll
    for (int kk = 0; kk < 64; kk += 32) {
      h8 af[4], bf[4];
#pragma unroll
      for (int m = 0; m < 4; ++m)
        af[m] = *(const h8*)(sA + (wr * 64 + m * 16 + colq) * 64 + kk + g * 8);
#pragma unroll
      for (int n = 0; n < 4; ++n)
        bf[n] = *(const h8*)(sB + (wc * 64 + n * 16 + colq) * 64 + kk + g * 8);
#pragma unroll
      for (int m = 0; m < 4; ++m)
#pragma unroll
        for (int n = 0; n < 4; ++n) acc[m][n] = mfma16(af[m], bf[n], acc[m][n]);
    }
    __syncthreads();
  }

#pragma unroll
  for (int n = 0; n < 4; ++n) {
    const int col = bn * 128 + wc * 64 + n * 16 + colq;
    const float bv = bias[col];
#pragma unroll
    for (int m = 0; m < 4; ++m) {
      const int row0 = bm * 128 + wr * 64 + m * 16 + 4 * g;
#pragma unroll
      for (int r = 0; r < 4; ++r) {
        float v = acc[m][n][r] + bv;
        if constexpr (F32OUT) {
          ((float*)Cp)[(size_t)(row0 + r) * N + col] = v;
        } else {
          ((f16*)Cp)[(size_t)(row0 + r) * N + col] = (f16)v;
        }
      }
    }
  }
}

// ---------------- RoPE apply: qkv[bt][f] -> Q[bh][t][d], K[bh][t][d] ----------------
// Q gets * (1/sqrt(128)) * log2(e) folded in (attention then uses exp2 with no extra scale).
__global__ __launch_bounds__(256) void k_rope(const f16* __restrict__ qkv,
                                              const float* __restrict__ tbl,
                                              f16* __restrict__ Q, f16* __restrict__ K) {
  int i = blockIdx.x * 256 + threadIdx.x;  // < 4096*16*64
  int d = i & 63;
  int h = (i >> 6) & 15;
  int bt = i >> 10;
  int t = bt & 2047;
  int bh = ((bt >> 11) << 4) | h;
  union { u32 u; f16 h2[2]; } qa, ka, qo, ko;
  qa.u = *(const u32*)(qkv + (size_t)bt * 6144 + h * 128 + 2 * d);
  ka.u = *(const u32*)(qkv + (size_t)bt * 6144 + 2048 + h * 128 + 2 * d);
  float c = tbl[2 * (t * 64 + d)];
  float s = tbl[2 * (t * 64 + d) + 1];
  float q0f = (float)qa.h2[0], q1f = (float)qa.h2[1];
  float k0f = (float)ka.h2[0], k1f = (float)ka.h2[1];
  const float SQ = 0.088388347648318447f * 1.4426950408889634f;
  qo.h2[0] = (f16)((q0f * c - q1f * s) * SQ);
  qo.h2[1] = (f16)((q1f * c + q0f * s) * SQ);
  ko.h2[0] = (f16)(k0f * c - k1f * s);
  ko.h2[1] = (f16)(k1f * c + k0f * s);
  *(u32*)(Q + ((size_t)bh * 2048 + t) * 128 + 2 * d) = qo.u;
  *(u32*)(K + ((size_t)bh * 2048 + t) * 128 + 2 * d) = ko.u;
}

// ---------------- V transpose: qkv[bt][4096 + h*128 + d] -> Vt[bh][d][t] ----------------
__global__ __launch_bounds__(256) void k_vtrans(const f16* __restrict__ qkv,
                                                f16* __restrict__ Vt) {
  __shared__ f16 ldsT[128 * 40];
  const int bh = blockIdx.y, t0 = blockIdx.x * 32;
  const int b = bh >> 4, h = bh & 15;
  const int tid = threadIdx.x;
#pragma unroll
  for (int cc = 0; cc < 2; ++cc) {
    int task = tid + cc * 256;  // 0..511
    int row = task >> 4;        // t-local 0..31
    int ch = task & 15;         // d chunk of 8
    h8 v = *(const h8*)(qkv + (size_t)(b * 2048 + t0 + row) * 6144 + 4096 + h * 128 + ch * 8);
#pragma unroll
    for (int j = 0; j < 8; ++j) ldsT[(ch * 8 + j) * 40 + row] = v[j];
  }
  __syncthreads();
  int d = tid >> 1, seg = tid & 1;
  h8 v0 = *(const h8*)(ldsT + d * 40 + seg * 16);
  h8 v1 = *(const h8*)(ldsT + d * 40 + seg * 16 + 8);
  f16* dst = Vt + ((size_t)bh * 128 + d) * 2048 + t0 + seg * 16;
  *(h8*)dst = v0;
  *(h8*)(dst + 8) = v1;
}

// ---------------- causal flash attention ----------------
// Linear grid of 1024 blocks, 4 waves/block, each wave owns 16 q-rows. KVBLK=64.
// bh = bid&31 (XCD round-robin -> 4 heads/XCD, KV working set ~4MB = one L2).
// q-tile via fold-interleave so each {c, c+256, c+512, c+768} bid set has equal work.
// Swapped QK^T: St[p][q] = sum_d K[p][d] Q[q][d] -> C-frag col = q (lane&15), row = p.
// PV as O^T[d][q] = sum_p V^T[d][p] P^T[p][q].
__global__ __launch_bounds__(256) void k_attn(const f16* __restrict__ Q,
                                              const f16* __restrict__ K,
                                              const f16* __restrict__ Vt,
                                              f16* __restrict__ O) {
  const int tid = threadIdx.x;
  const int w = tid >> 6, lane = tid & 63;
  const int g = lane >> 4, q = lane & 15;
  const int bid = blockIdx.x;
  const int bh = bid & 31;
  const int qtr = bid >> 5;  // 0..31
  const int qt = (qtr < 16) ? (2 * qtr) : (2 * (31 - qtr) + 1);
  const int q0 = (qt * 4 + w) * 16;

  const f16* Qb = Q + ((size_t)bh * 2048 + q0 + q) * 128;
  const f16* Kb = K + (size_t)bh * 2048 * 128 + (size_t)q * 128 + g * 8;
  const f16* Vb = Vt + ((size_t)bh * 128 + q) * 2048 + g * 8;

  h8 qf[4];
#pragma unroll
  for (int d4 = 0; d4 < 4; ++d4) qf[d4] = *(const h8*)(Qb + d4 * 32 + g * 8);

  f4 ot[8] = {};
  float mrun = -3.0e38f, lrun = 0.f;

  for (int kv0 = 0; kv0 < q0 + 16; kv0 += 64) {
    f4 st[4] = {{0.f, 0.f, 0.f, 0.f}, {0.f, 0.f, 0.f, 0.f},
                {0.f, 0.f, 0.f, 0.f}, {0.f, 0.f, 0.f, 0.f}};
    const f16* Kr = Kb + (size_t)kv0 * 128;
#pragma unroll
    for (int d4 = 0; d4 < 4; ++d4) {
#pragma unroll
      for (int s = 0; s < 4; ++s) {
        h8 kf = *(const h8*)(Kr + (size_t)s * 16 * 128 + d4 * 32);
        st[s] = mfma16(kf, qf[d4], st[s]);
      }
    }
    if (kv0 + 63 > q0) {  // causal mask (tiles near/past the diagonal)
#pragma unroll
      for (int s = 0; s < 4; ++s)
#pragma unroll
        for (int r = 0; r < 4; ++r)
          if (kv0 + s * 16 + 4 * g + r > q0 + q) st[s][r] = -3.0e38f;
    }
    // column max over {16 regs} x {lanes q, q+16, q+32, q+48}
    float pm = st[0][0];
#pragma unroll
    for (int s = 0; s < 4; ++s)
#pragma unroll
      for (int r = 0; r < 4; ++r) pm = fmaxf(pm, st[s][r]);
    pm = fmaxf(pm, __shfl_xor(pm, 16));
    pm = fmaxf(pm, __shfl_xor(pm, 32));
    // defer-max: only rescale when some column's max grew past mrun+8 (P <= 2^8)
    if (!__all(pm <= mrun + 8.0f)) {
      float mnew = fmaxf(mrun, pm);
      float corr = exp2f(mrun - mnew);
      lrun *= corr;
#pragma unroll
      for (int dt = 0; dt < 8; ++dt) ot[dt] *= corr;
      mrun = mnew;
    }
    float ps = 0.f;
#pragma unroll
    for (int s = 0; s < 4; ++s)
#pragma unroll
      for (int r = 0; r < 4; ++r) {
        st[s][r] = exp2f(st[s][r] - mrun);
        ps += st[s][r];
      }
    ps += __shfl_xor(ps, 16);
    ps += __shfl_xor(ps, 32);
    lrun += ps;

    // two 32-wide kv halves: pack P (C-frag) -> PV B-frag, then PV MFMAs
#pragma unroll
    for (int hh = 0; hh < 2; ++hh) {
      u32 wA0 = pkh2(st[2 * hh][0], st[2 * hh][1]);
      u32 wB0 = pkh2(st[2 * hh][2], st[2 * hh][3]);
      u32 wA1 = pkh2(st[2 * hh + 1][0], st[2 * hh + 1][1]);
      u32 wB1 = pkh2(st[2 * hh + 1][2], st[2 * hh + 1][3]);
      int s0 = ((g & 1) << 5) | q;
      u32 a0 = (u32)__shfl((int)wA0, s0),      a1 = (u32)__shfl((int)wA1, s0);
      u32 b0 = (u32)__shfl((int)wB0, s0),      b1 = (u32)__shfl((int)wB1, s0);
      u32 c0 = (u32)__shfl((int)wA0, s0 + 16), c1 = (u32)__shfl((int)wA1, s0 + 16);
      u32 d0 = (u32)__shfl((int)wB0, s0 + 16), d1 = (u32)__shfl((int)wB1, s0 + 16);
      union { u32 u[4]; h8 h; } pb;
      const bool hi = g >= 2;
      pb.u[0] = hi ? a1 : a0;
      pb.u[1] = hi ? b1 : b0;
      pb.u[2] = hi ? c1 : c0;
      pb.u[3] = hi ? d1 : d0;

      const f16* Vr = Vb + kv0 + 32 * hh;
#pragma unroll
      for (int dt = 0; dt < 8; ++dt) {
        h8 vf = *(const h8*)(Vr + (size_t)dt * 16 * 2048);
        ot[dt] = mfma16(vf, pb.h, ot[dt]);
      }
    }
  }

  float linv = 1.0f / lrun;
  f16* Ob = O + ((size_t)(bh >> 4) * 2048 + q0 + q) * 2048 + (bh & 15) * 128 + 4 * g;
#pragma unroll
  for (int dt = 0; dt < 8; ++dt) {
    union { f16 hh[4]; u64 u; } o;
#pragma unroll
    for (int r = 0; r < 4; ++r) o.hh[r] = (f16)(ot[dt][r] * linv);
    *(u64*)(Ob + dt * 16) = o.u;
  }
}

// ---------------- launch ----------------
extern "C" void kernel_launch(void* const* d_in, const int* in_sizes, int n_in,
                              void* d_out, int out_size, void* d_ws, size_t ws_size,
                              hipStream_t stream) {
  (void)in_sizes; (void)n_in; (void)out_size; (void)ws_size;
  const float* x    = (const float*)d_in[0];
  const float* Wqkv = (const float*)d_in[1];
  const float* bqkv = (const float*)d_in[2];
  const float* Wo   = (const float*)d_in[3];
  const float* bo   = (const float*)d_in[4];

  char* ws = (char*)d_ws;
  f16* xb    = (f16*)ws; ws += (size_t)4096 * 2048 * 2;
  f16* wqkvb = (f16*)ws; ws += (size_t)6144 * 2048 * 2;
  f16* wob   = (f16*)ws; ws += (size_t)2048 * 2048 * 2;
  f16* qkvb  = (f16*)ws; ws += (size_t)4096 * 6144 * 2;
  f16* Qb    = (f16*)ws; ws += (size_t)32 * 2048 * 128 * 2;
  f16* Kb    = (f16*)ws; ws += (size_t)32 * 2048 * 128 * 2;
  f16* Vtb   = (f16*)ws; ws += (size_t)32 * 128 * 2048 * 2;
  f16* attb  = (f16*)ws; ws += (size_t)4096 * 2048 * 2;
  float* tbl = (float*)ws; ws += (size_t)2048 * 64 * 2 * 4;

  k_cvt<<<8192, 256, 0, stream>>>(x, xb, 2097152);
  k_cvt<<<12288, 256, 0, stream>>>(Wqkv, wqkvb, 3145728);
  k_cvt<<<4096, 256, 0, stream>>>(Wo, wob, 1048576);
  k_rope_tbl<<<512, 256, 0, stream>>>(tbl);

  k_gemm_bt<0><<<dim3(48, 32), 256, 0, stream>>>(xb, wqkvb, bqkv, qkvb, 4096, 6144, 2048);

  k_rope<<<16384, 256, 0, stream>>>(qkvb, tbl, Qb, Kb);
  k_vtrans<<<dim3(64, 32), 256, 0, stream>>>(qkvb, Vtb);

  k_attn<<<1024, 256, 0, stream>>>(Qb, Kb, Vtb, attb);

  k_gemm_bt<1><<<dim3(16, 32), 256, 0, stream>>>(attb, wob, bo, d_out, 4096, 2048, 2048);
}

// Round 3
// 345.173 us; speedup vs baseline: 2.0159x; 1.5547x over previous
//
#include <hip/hip_runtime.h>

using f16 = _Float16;
typedef _Float16 h8 __attribute__((ext_vector_type(8)));
typedef _Float16 h4 __attribute__((ext_vector_type(4)));
typedef float f4 __attribute__((ext_vector_type(4)));
typedef unsigned int u32;
typedef unsigned long long u64;

#define DEVI static __device__ __forceinline__

DEVI f4 mfma16(h8 a, h8 b, f4 c) {
  return __builtin_amdgcn_mfma_f32_16x16x32_f16(a, b, c, 0, 0, 0);
}

// async global->LDS, 16B per lane. lds base must be wave-uniform; HW scatters lane i at base + i*16.
DEVI void gl_lds16(const f16* g, f16* l) {
  __builtin_amdgcn_global_load_lds(
      (const __attribute__((address_space(1))) u32*)g,
      (__attribute__((address_space(3))) u32*)l, 16, 0, 0);
}

DEVI u32 pkh2(float a, float b) {
  union { f16 h[2]; u32 u; } x;
  x.h[0] = (f16)a; x.h[1] = (f16)b;
  return x.u;
}

// ---------------- fp32 -> fp16 convert ----------------
typedef float fv4 __attribute__((ext_vector_type(4)));

__global__ __launch_bounds__(256) void k_cvt(const float* __restrict__ in,
                                             f16* __restrict__ out, int n4) {
  int i = blockIdx.x * 256 + threadIdx.x;
  if (i >= n4) return;
  fv4 v = ((const fv4*)in)[i];
  h4 o;
  o[0] = (f16)v[0]; o[1] = (f16)v[1]; o[2] = (f16)v[2]; o[3] = (f16)v[3];
  ((h4*)out)[i] = o;
}

// ---------------- RoPE cos/sin table ----------------
__global__ __launch_bounds__(256) void k_rope_tbl(float* __restrict__ tbl) {
  int i = blockIdx.x * 256 + threadIdx.x;  // 2048*64
  int t = i >> 6, d = i & 63;
  float invf = exp2f(-(float)d * (13.287712379549449f / 64.f));
  float a = (float)t * invf;
  tbl[2 * i]     = cosf(a);
  tbl[2 * i + 1] = sinf(a);
}

// ---------------- GEMM: C[M][N] = A[M][K] * Bt[N][K]^T + bias (m97 structure) ----------------
template <int F32OUT>
__global__ __launch_bounds__(256) void k_gemm_bt(const f16* __restrict__ A,
                                                 const f16* __restrict__ Bt,
                                                 const float* __restrict__ bias,
                                                 void* __restrict__ Cp,
                                                 int M, int N, int K) {
  __shared__ f16 lds[2 * 128 * 64];
  f16* sA = lds;
  f16* sB = lds + 128 * 64;
  const int tid = threadIdx.x;
  const int w = tid >> 6, lane = tid & 63;
  const int g = lane >> 4, colq = lane & 15;
  const int wr = w >> 1, wc = w & 1;
  const int bm = blockIdx.y, bn = blockIdx.x;

  f4 acc[4][4] = {};
  const int nk = K >> 6;
  const int lrow = lane >> 3;
  const int lch = lane & 7;

  for (int k0i = 0; k0i < nk; ++k0i) {
    const int k0 = k0i << 6;
#pragma unroll
    for (int c = 0; c < 4; ++c) {
      const int seg = c * 4 + w;
      const int row = seg * 8 + lrow;
      const f16* ga = A + (size_t)(bm * 128 + row) * K + k0 + lch * 8;
      const f16* gb = Bt + (size_t)(bn * 128 + row) * K + k0 + lch * 8;
      gl_lds16(ga, sA + seg * 512);
      gl_lds16(gb, sB + seg * 512);
    }
    __syncthreads();
#pragma unroll
    for (int kk = 0; kk < 64; kk += 32) {
      h8 af[4], bf[4];
#pragma unroll
      for (int m = 0; m < 4; ++m)
        af[m] = *(const h8*)(sA + (wr * 64 + m * 16 + colq) * 64 + kk + g * 8);
#pragma unroll
      for (int n = 0; n < 4; ++n)
        bf[n] = *(const h8*)(sB + (wc * 64 + n * 16 + colq) * 64 + kk + g * 8);
#pragma unroll
      for (int m = 0; m < 4; ++m)
#pragma unroll
        for (int n = 0; n < 4; ++n) acc[m][n] = mfma16(af[m], bf[n], acc[m][n]);
    }
    __syncthreads();
  }

#pragma unroll
  for (int n = 0; n < 4; ++n) {
    const int col = bn * 128 + wc * 64 + n * 16 + colq;
    const float bv = bias[col];
#pragma unroll
    for (int m = 0; m < 4; ++m) {
      const int row0 = bm * 128 + wr * 64 + m * 16 + 4 * g;
#pragma unroll
      for (int r = 0; r < 4; ++r) {
        float v = acc[m][n][r] + bv;
        if constexpr (F32OUT) {
          ((float*)Cp)[(size_t)(row0 + r) * N + col] = v;
        } else {
          ((f16*)Cp)[(size_t)(row0 + r) * N + col] = (f16)v;
        }
      }
    }
  }
}

// ---------------- RoPE apply ----------------
__global__ __launch_bounds__(256) void k_rope(const f16* __restrict__ qkv,
                                              const float* __restrict__ tbl,
                                              f16* __restrict__ Q, f16* __restrict__ K) {
  int i = blockIdx.x * 256 + threadIdx.x;  // < 4096*16*64
  int d = i & 63;
  int h = (i >> 6) & 15;
  int bt = i >> 10;
  int t = bt & 2047;
  int bh = ((bt >> 11) << 4) | h;
  union { u32 u; f16 h2[2]; } qa, ka, qo, ko;
  qa.u = *(const u32*)(qkv + (size_t)bt * 6144 + h * 128 + 2 * d);
  ka.u = *(const u32*)(qkv + (size_t)bt * 6144 + 2048 + h * 128 + 2 * d);
  float c = tbl[2 * (t * 64 + d)];
  float s = tbl[2 * (t * 64 + d) + 1];
  float q0f = (float)qa.h2[0], q1f = (float)qa.h2[1];
  float k0f = (float)ka.h2[0], k1f = (float)ka.h2[1];
  const float SQ = 0.088388347648318447f * 1.4426950408889634f;
  qo.h2[0] = (f16)((q0f * c - q1f * s) * SQ);
  qo.h2[1] = (f16)((q1f * c + q0f * s) * SQ);
  ko.h2[0] = (f16)(k0f * c - k1f * s);
  ko.h2[1] = (f16)(k1f * c + k0f * s);
  *(u32*)(Q + ((size_t)bh * 2048 + t) * 128 + 2 * d) = qo.u;
  *(u32*)(K + ((size_t)bh * 2048 + t) * 128 + 2 * d) = ko.u;
}

// ---------------- V transpose: qkv -> Vt[bh][d][t] ----------------
__global__ __launch_bounds__(256) void k_vtrans(const f16* __restrict__ qkv,
                                                f16* __restrict__ Vt) {
  __shared__ f16 ldsT[128 * 40];
  const int bh = blockIdx.y, t0 = blockIdx.x * 32;
  const int b = bh >> 4, h = bh & 15;
  const int tid = threadIdx.x;
#pragma unroll
  for (int cc = 0; cc < 2; ++cc) {
    int task = tid + cc * 256;
    int row = task >> 4;
    int ch = task & 15;
    h8 v = *(const h8*)(qkv + (size_t)(b * 2048 + t0 + row) * 6144 + 4096 + h * 128 + ch * 8);
#pragma unroll
    for (int j = 0; j < 8; ++j) ldsT[(ch * 8 + j) * 40 + row] = v[j];
  }
  __syncthreads();
  int d = tid >> 1, seg = tid & 1;
  h8 v0 = *(const h8*)(ldsT + d * 40 + seg * 16);
  h8 v1 = *(const h8*)(ldsT + d * 40 + seg * 16 + 8);
  f16* dst = Vt + ((size_t)bh * 128 + d) * 2048 + t0 + seg * 16;
  *(h8*)dst = v0;
  *(h8*)(dst + 8) = v1;
}

// ---------------- causal flash attention, LDS-staged, paired panels ----------------
// 256 blocks (1/CU), 4 waves, 32 q-rows/wave -> 128-row panel/phase.
// Block does panels {b, 15-b} sequentially: exactly 34 kv-64 iterations per block.
// Per iteration: K(64x128) + Vt(128x64) staged once in LDS (global_load_lds, 16B),
// double-buffered; stage(next) -> compute(cur) -> vmcnt(0) -> s_barrier.
// LDS XOR-swizzled via pre-swizzled global source (linear dest) + swizzled reads:
//   K slot(r,c) = r*16 + (c ^ ((r&7)<<1))   [16B slots, 16/row]  -> 2-way (free)
//   V slot(r,c) = r*8  + (c ^ (r&7))        [16B slots,  8/row]  -> 4-way
// Swapped QK^T (mfma(K,Q)): col=q lane, row=kv; PV: O^T[d][q] = Vt * P^T.
DEVI void stage_tiles(const f16* __restrict__ Kg, const f16* __restrict__ Vtg,
                      f16* bufK, f16* bufV, int kv, int w, int lane) {
#pragma unroll
  for (int jj = 0; jj < 4; ++jj) {
    const int j = w * 4 + jj;
    const int rK = j * 4 + (lane >> 4);
    const int cK = (lane & 15) ^ ((rK & 7) << 1);
    gl_lds16(Kg + (size_t)(kv + rK) * 128 + cK * 8, bufK + j * 512);
    const int rV = j * 8 + (lane >> 3);
    const int cV = (lane & 7) ^ (rV & 7);
    gl_lds16(Vtg + (size_t)rV * 2048 + kv + cV * 8, bufV + j * 512);
  }
}

__global__ __launch_bounds__(256, 1) void k_attn(const f16* __restrict__ Q,
                                                 const f16* __restrict__ K,
                                                 const f16* __restrict__ Vt,
                                                 f16* __restrict__ O) {
  __shared__ f16 lds[2][16384];  // per buffer: K tile [0,8192), V tile [8192,16384)
  const int tid = threadIdx.x;
  const int w = tid >> 6, lane = tid & 63;
  const int g = lane >> 4, q = lane & 15;
  const int bid = blockIdx.x;
  const int bh = bid & 31;   // head: XCD x serves heads {x, x+8, x+16, x+24}
  const int b = bid >> 5;    // pair index 0..7

  const f16* Kg = K + (size_t)bh * 2048 * 128;
  const f16* Vtg = Vt + (size_t)bh * 128 * 2048;
  const int qx2 = (q & 7) << 1;
  const int qx = q & 7;

  for (int ph = 0; ph < 2; ++ph) {
    const int p = ph ? (15 - b) : b;  // panel 0..15 (128 rows each)
    const int q0w = p * 128 + w * 32;
    const int nit = 2 * (p + 1);

    // Q fragments: 2 column sets (rows q0w+q and q0w+16+q)
    h8 qf[2][4];
#pragma unroll
    for (int set = 0; set < 2; ++set)
#pragma unroll
      for (int d4 = 0; d4 < 4; ++d4)
        qf[set][d4] = *(const h8*)(Q + ((size_t)bh * 2048 + q0w + 16 * set + q) * 128 + d4 * 32 + g * 8);

    stage_tiles(Kg, Vtg, lds[0], lds[0] + 8192, 0, w, lane);
    asm volatile("s_waitcnt vmcnt(0)" ::: "memory");
    __builtin_amdgcn_s_barrier();

    f4 ot[2][8] = {};
    float mrun[2] = {-3.0e38f, -3.0e38f};
    float lrun[2] = {0.f, 0.f};

    for (int it = 0; it < nit; ++it) {
      const int kv0 = it * 64;
      f16* bufK = lds[it & 1];
      f16* bufV = bufK + 8192;
      if (it + 1 < nit) {
        f16* nb = lds[(it + 1) & 1];
        stage_tiles(Kg, Vtg, nb, nb + 8192, kv0 + 64, w, lane);
      }
      if (kv0 < q0w + 32) {
        // ---- QK^T: 16 ds_reads feed 32 MFMAs ----
        f4 st[2][4] = {{{0.f,0.f,0.f,0.f},{0.f,0.f,0.f,0.f},{0.f,0.f,0.f,0.f},{0.f,0.f,0.f,0.f}},
                       {{0.f,0.f,0.f,0.f},{0.f,0.f,0.f,0.f},{0.f,0.f,0.f,0.f},{0.f,0.f,0.f,0.f}}};
#pragma unroll
        for (int d4 = 0; d4 < 4; ++d4) {
          h8 kf[4];
#pragma unroll
          for (int s = 0; s < 4; ++s)
            kf[s] = *(const h8*)(bufK + ((16 * s + q) * 16 + ((4 * d4 + g) ^ qx2)) * 8);
#pragma unroll
          for (int set = 0; set < 2; ++set)
#pragma unroll
            for (int s = 0; s < 4; ++s)
              st[set][s] = mfma16(kf[s], qf[set][d4], st[set][s]);
        }
        // ---- causal mask (near diagonal only) ----
        if (kv0 + 63 > q0w) {
#pragma unroll
          for (int set = 0; set < 2; ++set) {
            const int qcol = q0w + 16 * set + q;
#pragma unroll
            for (int s = 0; s < 4; ++s)
#pragma unroll
              for (int r = 0; r < 4; ++r)
                if (kv0 + s * 16 + 4 * g + r > qcol) st[set][s][r] = -3.0e38f;
          }
        }
        // ---- online softmax (per set), defer-max ----
        float pm[2];
#pragma unroll
        for (int set = 0; set < 2; ++set) {
          float m0 = st[set][0][0];
#pragma unroll
          for (int s = 0; s < 4; ++s)
#pragma unroll
            for (int r = 0; r < 4; ++r) m0 = fmaxf(m0, st[set][s][r]);
          m0 = fmaxf(m0, __shfl_xor(m0, 16));
          m0 = fmaxf(m0, __shfl_xor(m0, 32));
          pm[set] = m0;
        }
        const bool ok = (pm[0] <= mrun[0] + 8.0f) && (pm[1] <= mrun[1] + 8.0f);
        if (!__all(ok)) {
#pragma unroll
          for (int set = 0; set < 2; ++set) {
            float mnew = fmaxf(mrun[set], pm[set]);
            float corr = exp2f(mrun[set] - mnew);
            lrun[set] *= corr;
#pragma unroll
            for (int dt = 0; dt < 8; ++dt) ot[set][dt] *= corr;
            mrun[set] = mnew;
          }
        }
#pragma unroll
        for (int set = 0; set < 2; ++set) {
          float ps = 0.f;
#pragma unroll
          for (int s = 0; s < 4; ++s)
#pragma unroll
            for (int r = 0; r < 4; ++r) {
              st[set][s][r] = exp2f(st[set][s][r] - mrun[set]);
              ps += st[set][s][r];
            }
          ps += __shfl_xor(ps, 16);
          ps += __shfl_xor(ps, 32);
          lrun[set] += ps;
        }
        // ---- pack P (C-frag) -> PV B-frag, both sets/halves ----
        union { u32 u[4]; h8 h; } pb[2][2];
        const int s0l = ((g & 1) << 5) | q;
        const bool hi = g >= 2;
#pragma unroll
        for (int set = 0; set < 2; ++set)
#pragma unroll
          for (int hh = 0; hh < 2; ++hh) {
            u32 wA0 = pkh2(st[set][2 * hh][0], st[set][2 * hh][1]);
            u32 wB0 = pkh2(st[set][2 * hh][2], st[set][2 * hh][3]);
            u32 wA1 = pkh2(st[set][2 * hh + 1][0], st[set][2 * hh + 1][1]);
            u32 wB1 = pkh2(st[set][2 * hh + 1][2], st[set][2 * hh + 1][3]);
            u32 a0 = (u32)__shfl((int)wA0, s0l),      a1 = (u32)__shfl((int)wA1, s0l);
            u32 b0 = (u32)__shfl((int)wB0, s0l),      b1 = (u32)__shfl((int)wB1, s0l);
            u32 c0 = (u32)__shfl((int)wA0, s0l + 16), c1 = (u32)__shfl((int)wA1, s0l + 16);
            u32 d0 = (u32)__shfl((int)wB0, s0l + 16), d1 = (u32)__shfl((int)wB1, s0l + 16);
            pb[set][hh].u[0] = hi ? a1 : a0;
            pb[set][hh].u[1] = hi ? b1 : b0;
            pb[set][hh].u[2] = hi ? c1 : c0;
            pb[set][hh].u[3] = hi ? d1 : d0;
          }
        // ---- PV: 16 ds_reads feed 32 MFMAs ----
#pragma unroll
        for (int hh = 0; hh < 2; ++hh)
#pragma unroll
          for (int dt = 0; dt < 8; ++dt) {
            h8 vf = *(const h8*)(bufV + ((dt * 16 + q) * 8 + ((4 * hh + g) ^ qx)) * 8);
#pragma unroll
            for (int set = 0; set < 2; ++set)
              ot[set][dt] = mfma16(vf, pb[set][hh].h, ot[set][dt]);
          }
      }
      asm volatile("s_waitcnt vmcnt(0)" ::: "memory");
      __builtin_amdgcn_s_barrier();
    }

    // ---- epilogue: O[q-row][d], rows q0w+16*set+q ----
#pragma unroll
    for (int set = 0; set < 2; ++set) {
      float linv = 1.0f / lrun[set];
      f16* Ob = O + ((size_t)(bh >> 4) * 2048 + q0w + 16 * set + q) * 2048 + (bh & 15) * 128 + 4 * g;
#pragma unroll
      for (int dt = 0; dt < 8; ++dt) {
        union { f16 hh4[4]; u64 u; } o;
#pragma unroll
        for (int r = 0; r < 4; ++r) o.hh4[r] = (f16)(ot[set][dt][r] * linv);
        *(u64*)(Ob + dt * 16) = o.u;
      }
    }
  }
}

// ---------------- launch ----------------
extern "C" void kernel_launch(void* const* d_in, const int* in_sizes, int n_in,
                              void* d_out, int out_size, void* d_ws, size_t ws_size,
                              hipStream_t stream) {
  (void)in_sizes; (void)n_in; (void)out_size; (void)ws_size;
  const float* x    = (const float*)d_in[0];
  const float* Wqkv = (const float*)d_in[1];
  const float* bqkv = (const float*)d_in[2];
  const float* Wo   = (const float*)d_in[3];
  const float* bo   = (const float*)d_in[4];

  char* ws = (char*)d_ws;
  f16* xb    = (f16*)ws; ws += (size_t)4096 * 2048 * 2;
  f16* wqkvb = (f16*)ws; ws += (size_t)6144 * 2048 * 2;
  f16* wob   = (f16*)ws; ws += (size_t)2048 * 2048 * 2;
  f16* qkvb  = (f16*)ws; ws += (size_t)4096 * 6144 * 2;
  f16* Qb    = (f16*)ws; ws += (size_t)32 * 2048 * 128 * 2;
  f16* Kb    = (f16*)ws; ws += (size_t)32 * 2048 * 128 * 2;
  f16* Vtb   = (f16*)ws; ws += (size_t)32 * 128 * 2048 * 2;
  f16* attb  = (f16*)ws; ws += (size_t)4096 * 2048 * 2;
  float* tbl = (float*)ws; ws += (size_t)2048 * 64 * 2 * 4;

  k_cvt<<<8192, 256, 0, stream>>>(x, xb, 2097152);
  k_cvt<<<12288, 256, 0, stream>>>(Wqkv, wqkvb, 3145728);
  k_cvt<<<4096, 256, 0, stream>>>(Wo, wob, 1048576);
  k_rope_tbl<<<512, 256, 0, stream>>>(tbl);

  k_gemm_bt<0><<<dim3(48, 32), 256, 0, stream>>>(xb, wqkvb, bqkv, qkvb, 4096, 6144, 2048);

  k_rope<<<16384, 256, 0, stream>>>(qkvb, tbl, Qb, Kb);
  k_vtrans<<<dim3(64, 32), 256, 0, stream>>>(qkvb, Vtb);

  k_attn<<<256, 256, 0, stream>>>(Qb, Kb, Vtb, attb);

  k_gemm_bt<1><<<dim3(16, 32), 256, 0, stream>>>(attb, wob, bo, d_out, 4096, 2048, 2048);
}

// Round 4
// 317.923 us; speedup vs baseline: 2.1887x; 1.0857x over previous
//
#include <hip/hip_runtime.h>

using f16 = _Float16;
typedef _Float16 h8 __attribute__((ext_vector_type(8)));
typedef _Float16 h4 __attribute__((ext_vector_type(4)));
typedef float f4 __attribute__((ext_vector_type(4)));
typedef unsigned int u32;
typedef unsigned long long u64;

#define DEVI static __device__ __forceinline__

DEVI f4 mfma16(h8 a, h8 b, f4 c) {
  return __builtin_amdgcn_mfma_f32_16x16x32_f16(a, b, c, 0, 0, 0);
}

// async global->LDS, 16B per lane. lds base must be wave-uniform; HW scatters lane i at base + i*16.
DEVI void gl_lds16(const f16* g, f16* l) {
  __builtin_amdgcn_global_load_lds(
      (const __attribute__((address_space(1))) u32*)g,
      (__attribute__((address_space(3))) u32*)l, 16, 0, 0);
}

DEVI u32 pkh2(float a, float b) {
  union { f16 h[2]; u32 u; } x;
  x.h[0] = (f16)a; x.h[1] = (f16)b;
  return x.u;
}

// ---------------- fp32 -> fp16 convert ----------------
typedef float fv4 __attribute__((ext_vector_type(4)));

__global__ __launch_bounds__(256) void k_cvt(const float* __restrict__ in,
                                             f16* __restrict__ out, int n4) {
  int i = blockIdx.x * 256 + threadIdx.x;
  if (i >= n4) return;
  fv4 v = ((const fv4*)in)[i];
  h4 o;
  o[0] = (f16)v[0]; o[1] = (f16)v[1]; o[2] = (f16)v[2]; o[3] = (f16)v[3];
  ((h4*)out)[i] = o;
}

// ---------------- RoPE cos/sin table ----------------
__global__ __launch_bounds__(256) void k_rope_tbl(float* __restrict__ tbl) {
  int i = blockIdx.x * 256 + threadIdx.x;  // 2048*64
  int t = i >> 6, d = i & 63;
  float invf = exp2f(-(float)d * (13.287712379549449f / 64.f));
  float a = (float)t * invf;
  tbl[2 * i]     = cosf(a);
  tbl[2 * i + 1] = sinf(a);
}

// ---------------- GEMM: C[M][N] = A[M][K] * Bt[N][K]^T + bias ----------------
// BM=128, BN=256, BK=64. 8 waves (2x4), wave tile 64x64. Double-buffered LDS (96KB).
// Depth-2 counted-vmcnt pipeline (never vmcnt(0) in steady state):
//   iter t: ds_read all frags of KT t -> regs; lgkmcnt(0); barrier;
//           stage KT t+2 into just-consumed buffer (6 gl_lds/wave);
//           32 MFMA; vmcnt(6); barrier.
// At each end-barrier only KT t+2's loads are outstanding => KT t+1 landed for all waves.
// LDS XOR swizzle: phys_chunk = logical_chunk ^ (row&7), 16B chunks, 8/row.
// Staged with linear LDS dest + pre-swizzled GLOBAL source chunk (rule 21).
template <int F32OUT>
__global__ __launch_bounds__(512, 2) void k_gemm256(const f16* __restrict__ A,
                                                    const f16* __restrict__ Bt,
                                                    const float* __restrict__ bias,
                                                    void* __restrict__ Cp,
                                                    int M, int N, int K, int gy) {
  __shared__ f16 lds[2][24576];  // per buf: A[128][64] then B[256][64]
  const int tid = threadIdx.x;
  const int w = tid >> 6, lane = tid & 63;
  const int g = lane >> 4, colq = lane & 15;
  const int wr = w >> 2, wc = w & 3;

  // bijective XCD swizzle (gridDim.x % 8 == 0), bm-fast within XCD chunk
  const int nwg = gridDim.x;
  const int q8 = nwg >> 3;
  const int swz = (blockIdx.x & 7) * q8 + (blockIdx.x >> 3);
  const int bm = swz % gy, bn = swz / gy;

  const f16* Ab = A + (size_t)bm * 128 * K;
  const f16* Bb = Bt + (size_t)bn * 256 * K;

  const int srow = lane >> 3;               // 0..7
  const int schunk = (lane & 7) ^ srow;     // pre-swizzled source chunk
  const int nt = K >> 6;

  auto STAGE = [&](int kt, f16* buf) {
    const int k0 = kt << 6;
    f16* bA = buf;
    f16* bB = buf + 128 * 64;
#pragma unroll
    for (int j = 0; j < 2; ++j) {
      const int r = w * 16 + j * 8;  // + srow per lane
      gl_lds16(Ab + (size_t)(r + srow) * K + k0 + schunk * 8, bA + r * 64);
    }
#pragma unroll
    for (int j = 0; j < 4; ++j) {
      const int r = w * 32 + j * 8;
      gl_lds16(Bb + (size_t)(r + srow) * K + k0 + schunk * 8, bB + r * 64);
    }
  };

  // prologue: stage KT0, KT1; wait KT0 landed (KT1's 6 loads stay in flight)
  STAGE(0, lds[0]);
  STAGE(1, lds[1]);
  asm volatile("s_waitcnt vmcnt(6)" ::: "memory");
  __builtin_amdgcn_s_barrier();

  f4 acc[4][4] = {};
  const int rowA0 = wr * 64 + colq;
  const int rowB0 = wc * 64 + colq;
  const int cq7 = colq & 7;

  for (int t = 0; t < nt; ++t) {
    f16* cur = lds[t & 1];
    // ---- read all fragments of KT t into registers ----
    h8 af[2][4], bf[2][4];
#pragma unroll
    for (int kki = 0; kki < 2; ++kki) {
#pragma unroll
      for (int m = 0; m < 4; ++m)
        af[kki][m] = *(const h8*)(cur + (rowA0 + m * 16) * 64 + (((kki * 4 + g) ^ cq7) * 8));
#pragma unroll
      for (int n = 0; n < 4; ++n)
        bf[kki][n] = *(const h8*)(cur + 8192 + (rowB0 + n * 16) * 64 + (((kki * 4 + g) ^ cq7) * 8));
    }
    asm volatile("s_waitcnt lgkmcnt(0)" ::: "memory");
    __builtin_amdgcn_s_barrier();  // all waves done reading cur
    // ---- stage KT t+2 into cur (overwrite now safe) ----
    const bool more = (t + 2 < nt);
    if (more) STAGE(t + 2, cur);
    // ---- MFMA ----
    __builtin_amdgcn_s_setprio(1);
#pragma unroll
    for (int m = 0; m < 4; ++m)
#pragma unroll
      for (int n = 0; n < 4; ++n)
#pragma unroll
        for (int kki = 0; kki < 2; ++kki)
          acc[m][n] = mfma16(af[kki][m], bf[kki][n], acc[m][n]);
    __builtin_amdgcn_s_setprio(0);
    // ---- KT t+1 must be landed for all waves before next iteration ----
    if (more) {
      asm volatile("s_waitcnt vmcnt(6)" ::: "memory");
    } else {
      asm volatile("s_waitcnt vmcnt(0)" ::: "memory");
    }
    __builtin_amdgcn_s_barrier();
  }

  // ---- epilogue ----
#pragma unroll
  for (int n = 0; n < 4; ++n) {
    const int col = bn * 256 + wc * 64 + n * 16 + colq;
    const float bv = bias[col];
#pragma unroll
    for (int m = 0; m < 4; ++m) {
      const int row0 = bm * 128 + wr * 64 + m * 16 + 4 * g;
#pragma unroll
      for (int r = 0; r < 4; ++r) {
        float v = acc[m][n][r] + bv;
        if constexpr (F32OUT) {
          ((float*)Cp)[(size_t)(row0 + r) * N + col] = v;
        } else {
          ((f16*)Cp)[(size_t)(row0 + r) * N + col] = (f16)v;
        }
      }
    }
  }
}

// ---------------- RoPE apply ----------------
__global__ __launch_bounds__(256) void k_rope(const f16* __restrict__ qkv,
                                              const float* __restrict__ tbl,
                                              f16* __restrict__ Q, f16* __restrict__ K) {
  int i = blockIdx.x * 256 + threadIdx.x;  // < 4096*16*64
  int d = i & 63;
  int h = (i >> 6) & 15;
  int bt = i >> 10;
  int t = bt & 2047;
  int bh = ((bt >> 11) << 4) | h;
  union { u32 u; f16 h2[2]; } qa, ka, qo, ko;
  qa.u = *(const u32*)(qkv + (size_t)bt * 6144 + h * 128 + 2 * d);
  ka.u = *(const u32*)(qkv + (size_t)bt * 6144 + 2048 + h * 128 + 2 * d);
  float c = tbl[2 * (t * 64 + d)];
  float s = tbl[2 * (t * 64 + d) + 1];
  float q0f = (float)qa.h2[0], q1f = (float)qa.h2[1];
  float k0f = (float)ka.h2[0], k1f = (float)ka.h2[1];
  const float SQ = 0.088388347648318447f * 1.4426950408889634f;
  qo.h2[0] = (f16)((q0f * c - q1f * s) * SQ);
  qo.h2[1] = (f16)((q1f * c + q0f * s) * SQ);
  ko.h2[0] = (f16)(k0f * c - k1f * s);
  ko.h2[1] = (f16)(k1f * c + k0f * s);
  *(u32*)(Q + ((size_t)bh * 2048 + t) * 128 + 2 * d) = qo.u;
  *(u32*)(K + ((size_t)bh * 2048 + t) * 128 + 2 * d) = ko.u;
}

// ---------------- V transpose: qkv -> Vt[bh][d][t] ----------------
__global__ __launch_bounds__(256) void k_vtrans(const f16* __restrict__ qkv,
                                                f16* __restrict__ Vt) {
  __shared__ f16 ldsT[128 * 40];
  const int bh = blockIdx.y, t0 = blockIdx.x * 32;
  const int b = bh >> 4, h = bh & 15;
  const int tid = threadIdx.x;
#pragma unroll
  for (int cc = 0; cc < 2; ++cc) {
    int task = tid + cc * 256;
    int row = task >> 4;
    int ch = task & 15;
    h8 v = *(const h8*)(qkv + (size_t)(b * 2048 + t0 + row) * 6144 + 4096 + h * 128 + ch * 8);
#pragma unroll
    for (int j = 0; j < 8; ++j) ldsT[(ch * 8 + j) * 40 + row] = v[j];
  }
  __syncthreads();
  int d = tid >> 1, seg = tid & 1;
  h8 v0 = *(const h8*)(ldsT + d * 40 + seg * 16);
  h8 v1 = *(const h8*)(ldsT + d * 40 + seg * 16 + 8);
  f16* dst = Vt + ((size_t)bh * 128 + d) * 2048 + t0 + seg * 16;
  *(h8*)dst = v0;
  *(h8*)(dst + 8) = v1;
}

// ---------------- causal flash attention, LDS-staged, paired panels ----------------
DEVI void stage_tiles(const f16* __restrict__ Kg, const f16* __restrict__ Vtg,
                      f16* bufK, f16* bufV, int kv, int w, int lane) {
#pragma unroll
  for (int jj = 0; jj < 4; ++jj) {
    const int j = w * 4 + jj;
    const int rK = j * 4 + (lane >> 4);
    const int cK = (lane & 15) ^ ((rK & 7) << 1);
    gl_lds16(Kg + (size_t)(kv + rK) * 128 + cK * 8, bufK + j * 512);
    const int rV = j * 8 + (lane >> 3);
    const int cV = (lane & 7) ^ (rV & 7);
    gl_lds16(Vtg + (size_t)rV * 2048 + kv + cV * 8, bufV + j * 512);
  }
}

__global__ __launch_bounds__(256, 1) void k_attn(const f16* __restrict__ Q,
                                                 const f16* __restrict__ K,
                                                 const f16* __restrict__ Vt,
                                                 f16* __restrict__ O) {
  __shared__ f16 lds[2][16384];  // per buffer: K tile [0,8192), V tile [8192,16384)
  const int tid = threadIdx.x;
  const int w = tid >> 6, lane = tid & 63;
  const int g = lane >> 4, q = lane & 15;
  const int bid = blockIdx.x;
  const int bh = bid & 31;   // head: XCD x serves heads {x, x+8, x+16, x+24}
  const int b = bid >> 5;    // pair index 0..7

  const f16* Kg = K + (size_t)bh * 2048 * 128;
  const f16* Vtg = Vt + (size_t)bh * 128 * 2048;
  const int qx2 = (q & 7) << 1;
  const int qx = q & 7;

  for (int ph = 0; ph < 2; ++ph) {
    const int p = ph ? (15 - b) : b;  // panel 0..15 (128 rows each)
    const int q0w = p * 128 + w * 32;
    const int nit = 2 * (p + 1);

    h8 qf[2][4];
#pragma unroll
    for (int set = 0; set < 2; ++set)
#pragma unroll
      for (int d4 = 0; d4 < 4; ++d4)
        qf[set][d4] = *(const h8*)(Q + ((size_t)bh * 2048 + q0w + 16 * set + q) * 128 + d4 * 32 + g * 8);

    stage_tiles(Kg, Vtg, lds[0], lds[0] + 8192, 0, w, lane);
    asm volatile("s_waitcnt vmcnt(0)" ::: "memory");
    __builtin_amdgcn_s_barrier();

    f4 ot[2][8] = {};
    float mrun[2] = {-3.0e38f, -3.0e38f};
    float lrun[2] = {0.f, 0.f};

    for (int it = 0; it < nit; ++it) {
      const int kv0 = it * 64;
      f16* bufK = lds[it & 1];
      f16* bufV = bufK + 8192;
      if (it + 1 < nit) {
        f16* nb = lds[(it + 1) & 1];
        stage_tiles(Kg, Vtg, nb, nb + 8192, kv0 + 64, w, lane);
      }
      if (kv0 < q0w + 32) {
        f4 st[2][4] = {{{0.f,0.f,0.f,0.f},{0.f,0.f,0.f,0.f},{0.f,0.f,0.f,0.f},{0.f,0.f,0.f,0.f}},
                       {{0.f,0.f,0.f,0.f},{0.f,0.f,0.f,0.f},{0.f,0.f,0.f,0.f},{0.f,0.f,0.f,0.f}}};
#pragma unroll
        for (int d4 = 0; d4 < 4; ++d4) {
          h8 kf[4];
#pragma unroll
          for (int s = 0; s < 4; ++s)
            kf[s] = *(const h8*)(bufK + ((16 * s + q) * 16 + ((4 * d4 + g) ^ qx2)) * 8);
#pragma unroll
          for (int set = 0; set < 2; ++set)
#pragma unroll
            for (int s = 0; s < 4; ++s)
              st[set][s] = mfma16(kf[s], qf[set][d4], st[set][s]);
        }
        if (kv0 + 63 > q0w) {
#pragma unroll
          for (int set = 0; set < 2; ++set) {
            const int qcol = q0w + 16 * set + q;
#pragma unroll
            for (int s = 0; s < 4; ++s)
#pragma unroll
              for (int r = 0; r < 4; ++r)
                if (kv0 + s * 16 + 4 * g + r > qcol) st[set][s][r] = -3.0e38f;
          }
        }
        float pm[2];
#pragma unroll
        for (int set = 0; set < 2; ++set) {
          float m0 = st[set][0][0];
#pragma unroll
          for (int s = 0; s < 4; ++s)
#pragma unroll
            for (int r = 0; r < 4; ++r) m0 = fmaxf(m0, st[set][s][r]);
          m0 = fmaxf(m0, __shfl_xor(m0, 16));
          m0 = fmaxf(m0, __shfl_xor(m0, 32));
          pm[set] = m0;
        }
        const bool ok = (pm[0] <= mrun[0] + 8.0f) && (pm[1] <= mrun[1] + 8.0f);
        if (!__all(ok)) {
#pragma unroll
          for (int set = 0; set < 2; ++set) {
            float mnew = fmaxf(mrun[set], pm[set]);
            float corr = exp2f(mrun[set] - mnew);
            lrun[set] *= corr;
#pragma unroll
            for (int dt = 0; dt < 8; ++dt) ot[set][dt] *= corr;
            mrun[set] = mnew;
          }
        }
#pragma unroll
        for (int set = 0; set < 2; ++set) {
          float ps = 0.f;
#pragma unroll
          for (int s = 0; s < 4; ++s)
#pragma unroll
            for (int r = 0; r < 4; ++r) {
              st[set][s][r] = exp2f(st[set][s][r] - mrun[set]);
              ps += st[set][s][r];
            }
          ps += __shfl_xor(ps, 16);
          ps += __shfl_xor(ps, 32);
          lrun[set] += ps;
        }
        union { u32 u[4]; h8 h; } pb[2][2];
        const int s0l = ((g & 1) << 5) | q;
        const bool hi = g >= 2;
#pragma unroll
        for (int set = 0; set < 2; ++set)
#pragma unroll
          for (int hh = 0; hh < 2; ++hh) {
            u32 wA0 = pkh2(st[set][2 * hh][0], st[set][2 * hh][1]);
            u32 wB0 = pkh2(st[set][2 * hh][2], st[set][2 * hh][3]);
            u32 wA1 = pkh2(st[set][2 * hh + 1][0], st[set][2 * hh + 1][1]);
            u32 wB1 = pkh2(st[set][2 * hh + 1][2], st[set][2 * hh + 1][3]);
            u32 a0 = (u32)__shfl((int)wA0, s0l),      a1 = (u32)__shfl((int)wA1, s0l);
            u32 b0 = (u32)__shfl((int)wB0, s0l),      b1 = (u32)__shfl((int)wB1, s0l);
            u32 c0 = (u32)__shfl((int)wA0, s0l + 16), c1 = (u32)__shfl((int)wA1, s0l + 16);
            u32 d0 = (u32)__shfl((int)wB0, s0l + 16), d1 = (u32)__shfl((int)wB1, s0l + 16);
            pb[set][hh].u[0] = hi ? a1 : a0;
            pb[set][hh].u[1] = hi ? b1 : b0;
            pb[set][hh].u[2] = hi ? c1 : c0;
            pb[set][hh].u[3] = hi ? d1 : d0;
          }
#pragma unroll
        for (int hh = 0; hh < 2; ++hh)
#pragma unroll
          for (int dt = 0; dt < 8; ++dt) {
            h8 vf = *(const h8*)(bufV + ((dt * 16 + q) * 8 + ((4 * hh + g) ^ qx)) * 8);
#pragma unroll
            for (int set = 0; set < 2; ++set)
              ot[set][dt] = mfma16(vf, pb[set][hh].h, ot[set][dt]);
          }
      }
      asm volatile("s_waitcnt vmcnt(0)" ::: "memory");
      __builtin_amdgcn_s_barrier();
    }

#pragma unroll
    for (int set = 0; set < 2; ++set) {
      float linv = 1.0f / lrun[set];
      f16* Ob = O + ((size_t)(bh >> 4) * 2048 + q0w + 16 * set + q) * 2048 + (bh & 15) * 128 + 4 * g;
#pragma unroll
      for (int dt = 0; dt < 8; ++dt) {
        union { f16 hh4[4]; u64 u; } o;
#pragma unroll
        for (int r = 0; r < 4; ++r) o.hh4[r] = (f16)(ot[set][dt][r] * linv);
        *(u64*)(Ob + dt * 16) = o.u;
      }
    }
  }
}

// ---------------- launch ----------------
extern "C" void kernel_launch(void* const* d_in, const int* in_sizes, int n_in,
                              void* d_out, int out_size, void* d_ws, size_t ws_size,
                              hipStream_t stream) {
  (void)in_sizes; (void)n_in; (void)out_size; (void)ws_size;
  const float* x    = (const float*)d_in[0];
  const float* Wqkv = (const float*)d_in[1];
  const float* bqkv = (const float*)d_in[2];
  const float* Wo   = (const float*)d_in[3];
  const float* bo   = (const float*)d_in[4];

  char* ws = (char*)d_ws;
  f16* xb    = (f16*)ws; ws += (size_t)4096 * 2048 * 2;
  f16* wqkvb = (f16*)ws; ws += (size_t)6144 * 2048 * 2;
  f16* wob   = (f16*)ws; ws += (size_t)2048 * 2048 * 2;
  f16* qkvb  = (f16*)ws; ws += (size_t)4096 * 6144 * 2;
  f16* Qb    = (f16*)ws; ws += (size_t)32 * 2048 * 128 * 2;
  f16* Kb    = (f16*)ws; ws += (size_t)32 * 2048 * 128 * 2;
  f16* Vtb   = (f16*)ws; ws += (size_t)32 * 128 * 2048 * 2;
  f16* attb  = (f16*)ws; ws += (size_t)4096 * 2048 * 2;
  float* tbl = (float*)ws; ws += (size_t)2048 * 64 * 2 * 4;

  k_cvt<<<8192, 256, 0, stream>>>(x, xb, 2097152);
  k_cvt<<<12288, 256, 0, stream>>>(Wqkv, wqkvb, 3145728);
  k_cvt<<<4096, 256, 0, stream>>>(Wo, wob, 1048576);
  k_rope_tbl<<<512, 256, 0, stream>>>(tbl);

  // QKV: M=4096 (gy=32), N=6144 (gx=24) -> 768 blocks (3 exact rounds of 256 CUs)
  k_gemm256<0><<<768, 512, 0, stream>>>(xb, wqkvb, bqkv, qkvb, 4096, 6144, 2048, 32);

  k_rope<<<16384, 256, 0, stream>>>(qkvb, tbl, Qb, Kb);
  k_vtrans<<<dim3(64, 32), 256, 0, stream>>>(qkvb, Vtb);

  k_attn<<<256, 256, 0, stream>>>(Qb, Kb, Vtb, attb);

  // out-proj: M=4096 (gy=32), N=2048 (gx=8) -> 256 blocks (1 exact round)
  k_gemm256<1><<<256, 512, 0, stream>>>(attb, wob, bo, d_out, 4096, 2048, 2048, 32);
}